// Round 18
// baseline (384.721 us; speedup 1.0000x reference)
//
#include <hip/hip_runtime.h>
#include <hip/hip_bf16.h>
#include <stdint.h>

#define NN 50000
#define RR 5
#define AA 8
#define FF 128
#define TT 2
#define OO 128
#define KDIM 1024   // 8 planes * F
#define KB 512      // K per half (E or O)
#define RA 40       // R*A

typedef __attribute__((ext_vector_type(8))) short short8;
typedef __attribute__((ext_vector_type(4))) float f32x4;
typedef __attribute__((ext_vector_type(2))) float f32x2;
typedef __attribute__((ext_vector_type(4))) int i32x4;
typedef __attribute__((ext_vector_type(2))) unsigned u32x2;

#if __has_builtin(__builtin_elementwise_fma)
__device__ inline f32x2 pk_fma(f32x2 a, f32x2 b, f32x2 c) {
  return __builtin_elementwise_fma(a, b, c);
}
#else
__device__ inline f32x2 pk_fma(f32x2 a, f32x2 b, f32x2 c) {
  f32x2 d;
  asm("v_pk_fma_f32 %0, %1, %2, %3" : "=v"(d) : "v"(a), "v"(b), "v"(c));
  return d;
}
#endif

__device__ inline void gload_lds16(const void* g, void* l) {
  __builtin_amdgcn_global_load_lds(
      (const __attribute__((address_space(1))) unsigned int*)g,
      (__attribute__((address_space(3))) unsigned int*)l, 16, 0, 0);
}

// ---------- prep: mesh->bf16 sliced, G (radix-2 mix), B2 (E/O weights in
// MFMA-fragment-major layout), packed bary ----------
__global__ void prep_kernel(const float* __restrict__ mesh,
                            const float* __restrict__ coeffs,
                            const float* __restrict__ W,
                            const float* __restrict__ bary_w,
                            const int* __restrict__ bary_idx,
                            __hip_bfloat16* __restrict__ meshq,  // [4][N][32]
                            float* __restrict__ G,               // [8][40]
                            __hip_bfloat16* __restrict__ B2,     // 2MB frag-major
                            unsigned* __restrict__ packb,
                            int do_pack) {
  int tid = blockIdx.x * blockDim.x + threadIdx.x;
  int stride = gridDim.x * blockDim.x;
  for (int i = tid; i < NN * FF; i += stride) {
    int n = i >> 7, f = i & 127;
    int p = f >> 5, fo = f & 31;
    meshq[((long)p * NN + n) * 32 + fo] = __float2bfloat16(mesh[i]);
  }
  // G[p][k]: p<4 -> C2[p]+C2[p+4];  p>=4 -> C2[p-4]-C2[p]   (C2 = sum_r coeffs)
  for (int i = tid; i < AA * RA; i += stride) {
    int p = i / RA, k = i % RA;
    int a = p & 3;
    float s1 = 0.f, s2 = 0.f;
    for (int r = 0; r < RR; ++r) {
      s1 += coeffs[(r * AA + a) * RA + k];
      s2 += coeffs[(r * AA + a + 4) * RA + k];
    }
    G[i] = (p < 4) ? (s1 + s2) : (s1 - s2);
  }
  // B2: e -> sub=e&7, lane=(e>>3)&63, kt=(e>>9)&15, cg=(e>>13)&63, half=e>>19.
  // col c = cg*16+(lane&15), k = kt*32+(lane>>4)*8+sub; c = o*8+t*4+j.
  for (int e = tid; e < 2048 * KB; e += stride) {
    int sub = e & 7;
    int lane = (e >> 3) & 63;
    int kt = (e >> 9) & 15;
    int cg = (e >> 13) & 63;
    int half = e >> 19;
    int c = cg * 16 + (lane & 15);
    int k = kt * 32 + (lane >> 4) * 8 + sub;
    int o = c >> 3, t = (c >> 2) & 1, j = c & 3;
    int a4 = k >> 7, f = k & 127;
    int m = (a4 + j) & 3;
    float w0 = W[((m * TT + t) * OO + o) * FF + f];
    float w4 = W[(((m + 4) * TT + t) * OO + o) * FF + f];
    float v;
    if (half == 0) v = 0.5f * (w0 + w4);
    else {
      v = 0.5f * (w0 - w4);
      if (a4 + j >= 4) v = -v;
    }
    B2[e] = __float2bfloat16(v);
  }
  if (do_pack) {
    for (int i = tid; i < NN * 120; i += stride) {
      __hip_bfloat16 h = __float2bfloat16(bary_w[i]);
      unsigned wb = *(unsigned short*)&h;
      packb[i] = ((unsigned)bary_idx[i] << 16) | wb;
    }
  }
}

// ---------- S pass (packed, per-slice, 4 features/lane, pk-f32, unroll 4) ----------
__global__ __launch_bounds__(256) void s_pass_packed(
    const __hip_bfloat16* __restrict__ meshq,
    const unsigned* __restrict__ packb,
    const float* __restrict__ G,
    __hip_bfloat16* __restrict__ Sout,
    int p) {
  __shared__ unsigned pk_s[32 * 120];
  __shared__ float g_s[AA * RA];
  int tid = threadIdx.x;
  long n0 = (long)blockIdx.x * 32;
  int nnode = (NN - n0 < 32) ? (int)(NN - n0) : 32;
  int nvec = nnode * 30;
  const i32x4* psrc = (const i32x4*)(packb + n0 * 120);
  for (int i = tid; i < nvec; i += 256) {
    i32x4 v = __builtin_nontemporal_load(psrc + i);
    ((i32x4*)pk_s)[i] = v;
  }
  for (int i = tid; i < AA * RA; i += 256) g_s[i] = G[i];
  __syncthreads();

  int g = tid >> 3;
  int fo = tid & 7;
  long n = n0 + g;
  if (n >= NN) return;
  const unsigned* pg = pk_s + g * 120;
  const char* mbase = (const char*)meshq + (long)p * NN * 64 + fo * 8;

  f32x2 accA[AA], accB[AA];
#pragma unroll
  for (int a = 0; a < AA; ++a) {
    accA[a] = (f32x2){0.f, 0.f};
    accB[a] = (f32x2){0.f, 0.f};
  }

#pragma unroll 4
  for (int k = 0; k < RA; ++k) {
    f32x2 sA = (f32x2){0.f, 0.f}, sB = (f32x2){0.f, 0.f};
#pragma unroll
    for (int j = 0; j < 3; ++j) {
      unsigned v = pg[k * 3 + j];
      long row = v >> 16;
      float w = __uint_as_float(v << 16);
      f32x2 wv = (f32x2){w, w};
      u32x2 u = *(const u32x2*)(mbase + row * 64);
      f32x2 lo = (f32x2){__uint_as_float(u[0] << 16),
                         __uint_as_float(u[0] & 0xffff0000u)};
      f32x2 hi = (f32x2){__uint_as_float(u[1] << 16),
                         __uint_as_float(u[1] & 0xffff0000u)};
      sA = pk_fma(wv, lo, sA);
      sB = pk_fma(wv, hi, sB);
    }
#pragma unroll
    for (int a = 0; a < AA; ++a) {
      float cc = g_s[a * RA + k];
      f32x2 cv = (f32x2){cc, cc};
      accA[a] = pk_fma(cv, sA, accA[a]);
      accB[a] = pk_fma(cv, sB, accB[a]);
    }
  }

  long base = n * KDIM + p * 32 + fo * 4;
#pragma unroll
  for (int a = 0; a < AA; ++a) {
    __hip_bfloat16 h0 = __float2bfloat16(accA[a][0]);
    __hip_bfloat16 h1 = __float2bfloat16(accA[a][1]);
    __hip_bfloat16 h2 = __float2bfloat16(accB[a][0]);
    __hip_bfloat16 h3 = __float2bfloat16(accB[a][1]);
    unsigned w0 = (unsigned)*(unsigned short*)&h0 |
                  ((unsigned)*(unsigned short*)&h1 << 16);
    unsigned w1 = (unsigned)*(unsigned short*)&h2 |
                  ((unsigned)*(unsigned short*)&h3 << 16);
    u32x2 st = (u32x2){w0, w1};
    __builtin_nontemporal_store(st, (u32x2*)(Sout + base + a * FF));
  }
}

// ---------- S pass (legacy fallback, per-slice) ----------
__global__ __launch_bounds__(256) void s_pass_kernel(
    const __hip_bfloat16* __restrict__ meshq,
    const float* __restrict__ bary_w,
    const int* __restrict__ bary_idx,
    const float* __restrict__ G,
    __hip_bfloat16* __restrict__ Sout,
    int p) {
  __shared__ float w_s[16 * 120];
  __shared__ int i_s[16 * 120];
  __shared__ float g_s[AA * RA];
  int tid = threadIdx.x;
  long n0 = (long)blockIdx.x * 16;
  const f32x4* wsrc = (const f32x4*)(bary_w + n0 * 120);
  const i32x4* isrc = (const i32x4*)(bary_idx + n0 * 120);
  for (int i = tid; i < 480; i += 256) {
    f32x4 wv = __builtin_nontemporal_load(wsrc + i);
    ((f32x4*)w_s)[i] = wv;
    i32x4 iv = __builtin_nontemporal_load(isrc + i);
    ((i32x4*)i_s)[i] = iv;
  }
  for (int i = tid; i < AA * RA; i += 256) g_s[i] = G[i];
  __syncthreads();
  int g = tid >> 4;
  int fo = tid & 15;
  long n = n0 + g;
  const float* wg = w_s + g * 120;
  const int* ig = i_s + g * 120;
  const char* mbase = (const char*)meshq + (long)p * NN * 64 + fo * 4;
  float sx_acc[AA], sy_acc[AA];
#pragma unroll
  for (int a = 0; a < AA; ++a) { sx_acc[a] = 0.f; sy_acc[a] = 0.f; }
#pragma unroll 2
  for (int k = 0; k < RA; ++k) {
    float sx = 0.f, sy = 0.f;
#pragma unroll
    for (int j = 0; j < 3; ++j) {
      int row = ig[k * 3 + j];
      unsigned u = *(const unsigned*)(mbase + (long)row * 64);
      float w = wg[k * 3 + j];
      sx += w * __uint_as_float(u << 16);
      sy += w * __uint_as_float(u & 0xffff0000u);
    }
#pragma unroll
    for (int a = 0; a < AA; ++a) {
      float c = g_s[a * RA + k];
      sx_acc[a] += c * sx;
      sy_acc[a] += c * sy;
    }
  }
  long base = n * KDIM + p * 32 + fo * 2;
#pragma unroll
  for (int a = 0; a < AA; ++a) {
    __hip_bfloat16 hx = __float2bfloat16(sx_acc[a]);
    __hip_bfloat16 hy = __float2bfloat16(sy_acc[a]);
    unsigned u = (unsigned)*(unsigned short*)&hx | ((unsigned)*(unsigned short*)&hy << 16);
    __builtin_nontemporal_store(u, (unsigned*)(Sout + base + a * FF));
  }
}

// ---------- GEMM (radix-2, SMALL-ACC 3-waves/SIMD): block = 64 rows x
// (128E + 128O cols), K=512; 256 thr = 4 waves (2M x 2N); per wave 32 rows x
// 64 cols per half -> acc[2][8] f32x4 = 64 AGPR (~155 total regs, fits
// 512/3=170 cap). Occupancy was THE invariant limiter (21% in every config:
// 128 VGPR + 128 acc-AGPR = 256 -> 2 waves/SIMD). launch_bounds(256,3) buys a
// 3rd wave/SIMD. LDS 48KB = 2 x (A 8KB + B-fragmajor 16KB); B ds_reads are
// lane-linear (conflict-free, no swizzle). grid (8, 784): cb = by&7,
// mt = (by>>3)*8 + bx (XCD A-share).
__global__ __launch_bounds__(256, 3) void gemm_kernel(
    const __hip_bfloat16* __restrict__ Sh,
    const __hip_bfloat16* __restrict__ B2,
    const float* __restrict__ bias,
    float* __restrict__ out) {
  int bx = blockIdx.x;
  int by = blockIdx.y;
  int cb = by & 7;
  int mt = ((by >> 3) << 3) + bx;
  if (mt >= 782) return;
  int row0 = mt * 64;

  int tid = threadIdx.x;
  int lane = tid & 63;
  int wid = tid >> 6;
  int wave_m = wid >> 1;   // 0..1 (32 rows each)
  int wave_n = wid & 1;    // 0..1 (64 cols each per half)

  // buffer b: [b*24576, +8192) A (Sp 4K | Sm 4K); [+8192, +24576) B frag-major
  // (half*8192 + cgl*1024 + lane*16). Epilogue lout = 64 x 156 floats (39936B).
  __shared__ __align__(16) char lds[49152];

  // A staging: 512 x 16B; li -> plane = li>>8, r = (li&255)>>2, sp = li&3
  long srcA[2];
  int dstA[2];
#pragma unroll
  for (int i = 0; i < 2; ++i) {
    int li = i * 256 + tid;
    int plane = li >> 8;
    int r = (li & 255) >> 2, sp = li & 3;
    int sl = sp ^ ((r >> 1) & 3);
    int rowA = row0 + r;
    if (rowA >= NN) rowA = NN - 1;
    srcA[i] = (long)rowA * KDIM + plane * 512 + sl * 8;
    dstA[i] = li * 16;  // plane*4096 + (li&255)*16
  }
  // B staging: 1024 x 16B straight copy of frag-major B2 slice (cb, kt=STP)
  const char* b2c = (const char*)B2;
  long srcB[4];
  int dstB[4];
#pragma unroll
  for (int i = 0; i < 4; ++i) {
    int li = i * 256 + tid;
    int half = li >> 9, cgl = (li >> 6) & 7, inner = li & 63;
    srcB[i] = (((long)(half * 64 + cb * 8 + cgl) * 16) * 1024) + inner * 16;
    dstB[i] = 8192 + li * 16;
  }
  // A frag read offsets (swizzled); b frag offsets (lane-linear)
  int offA[2];
#pragma unroll
  for (int m = 0; m < 2; ++m) {
    int r = wave_m * 32 + m * 16 + (lane & 15);
    int phys = (lane >> 4) ^ ((r >> 1) & 3);
    offA[m] = r * 64 + phys * 16;
  }
  int offB[4];
#pragma unroll
  for (int n = 0; n < 4; ++n)
    offB[n] = 8192 + (wave_n * 4 + n) * 1024 + lane * 16;

  f32x4 acc[2][8];  // [m][n<4: E, n>=4: O]
#pragma unroll
  for (int m = 0; m < 2; ++m)
#pragma unroll
    for (int q = 0; q < 8; ++q) acc[m][q] = (f32x4){0.f, 0.f, 0.f, 0.f};

#define STAGE(T)                                                              \
  {                                                                           \
    char* base_ = lds + ((T) & 1) * 24576;                                    \
    long k0_ = (long)(T) * 32;                                                \
    _Pragma("unroll") for (int i_ = 0; i_ < 2; ++i_)                          \
        gload_lds16(Sh + srcA[i_] + k0_, base_ + dstA[i_]);                   \
    _Pragma("unroll") for (int i_ = 0; i_ < 4; ++i_)                          \
        gload_lds16(b2c + srcB[i_] + (long)(T) * 1024, base_ + dstB[i_]);     \
  }

#define GSTEP(STP, DOSTAGE)                                                   \
  {                                                                           \
    const char* cbuf = lds + ((STP) & 1) * 24576;                             \
    asm volatile("s_waitcnt vmcnt(0)" ::: "memory");                          \
    __builtin_amdgcn_sched_barrier(0);                                        \
    __builtin_amdgcn_s_barrier();                                             \
    __builtin_amdgcn_sched_barrier(0);                                        \
    if (DOSTAGE) STAGE((STP) + 1)                                             \
    __builtin_amdgcn_sched_barrier(0);                                        \
    short8 aE[2], aO[2], bE[4], bO[4];                                        \
    _Pragma("unroll") for (int m_ = 0; m_ < 2; ++m_) {                        \
      aE[m_] = *(const short8*)(cbuf + offA[m_]);                             \
      aO[m_] = *(const short8*)(cbuf + offA[m_] + 4096);                      \
    }                                                                         \
    _Pragma("unroll") for (int n_ = 0; n_ < 4; ++n_) {                        \
      bE[n_] = *(const short8*)(cbuf + offB[n_]);                             \
      bO[n_] = *(const short8*)(cbuf + offB[n_] + 8192);                      \
    }                                                                         \
    __builtin_amdgcn_s_setprio(1);                                            \
    _Pragma("unroll") for (int m_ = 0; m_ < 2; ++m_)                          \
        _Pragma("unroll") for (int n_ = 0; n_ < 4; ++n_) {                    \
      acc[m_][n_] = __builtin_amdgcn_mfma_f32_16x16x32_bf16(                  \
          aE[m_], bE[n_], acc[m_][n_], 0, 0, 0);                              \
      acc[m_][n_ + 4] = __builtin_amdgcn_mfma_f32_16x16x32_bf16(              \
          aO[m_], bO[n_], acc[m_][n_ + 4], 0, 0, 0);                          \
    }                                                                         \
    __builtin_amdgcn_s_setprio(0);                                            \
    __builtin_amdgcn_sched_barrier(0);                                        \
  }

  STAGE(0)
  GSTEP(0, 1)  GSTEP(1, 1)  GSTEP(2, 1)  GSTEP(3, 1)
  GSTEP(4, 1)  GSTEP(5, 1)  GSTEP(6, 1)  GSTEP(7, 1)
  GSTEP(8, 1)  GSTEP(9, 1)  GSTEP(10, 1) GSTEP(11, 1)
  GSTEP(12, 1) GSTEP(13, 1) GSTEP(14, 1) GSTEP(15, 0)

  // ---- epilogue: z = E +- O, +40*bias, relu, t-sum shfl_xor(4) -> lout
  //      (64 rows x 156 floats) -> coalesced float4 copy ----
  __syncthreads();
  float* lout = (float*)lds;
  int c = lane & 15;
  int t = (c >> 2) & 1;
  int j = c & 3;
  int hi = lane >> 4;
  float bq[4];
#pragma unroll
  for (int n = 0; n < 4; ++n) {
    int o_l = wave_n * 8 + n * 2 + (c >> 3);
    bq[n] = 40.f * bias[t * OO + cb * 16 + o_l];
  }
#pragma unroll
  for (int m = 0; m < 2; ++m) {
#pragma unroll
    for (int n = 0; n < 4; ++n) {
      int o_l = wave_n * 8 + n * 2 + (c >> 3);
#pragma unroll
      for (int i = 0; i < 4; ++i) {
        float zE = acc[m][n][i];
        float zO = acc[m][n + 4][i];
        float rlo = fmaxf(zE + zO + bq[n], 0.f);
        float rhi = fmaxf(zE - zO + bq[n], 0.f);
        rlo += __shfl_xor(rlo, 4);
        rhi += __shfl_xor(rhi, 4);
        if (!(lane & 4)) {
          int cl = wave_m * 32 + m * 16 + hi * 4 + i;
          lout[cl * 156 + j * 20 + o_l] = rlo;
          lout[cl * 156 + (j + 4) * 20 + o_l] = rhi;
        }
      }
    }
  }
  __syncthreads();
  // copy: 64 rows x 8 kr x 4 float4 = 2048 float4, 256 thr -> 8 iters
#pragma unroll
  for (int it = 0; it < 8; ++it) {
    int gi = it * 256 + tid;
    int cl = gi >> 5;
    int rem = gi & 31;
    int kr = rem >> 2, q = rem & 3;
    int grow = row0 + cl;
    if (grow < NN) {
      f32x4 v = *(const f32x4*)(lout + cl * 156 + kr * 20 + q * 4);
      long gaddr = (long)grow * 1024 + kr * 128 + cb * 16 + q * 4;
      __builtin_nontemporal_store(v, (f32x4*)(out + gaddr));
    }
  }
}

extern "C" void kernel_launch(void* const* d_in, const int* in_sizes, int n_in,
                              void* d_out, int out_size, void* d_ws, size_t ws_size,
                              hipStream_t stream) {
  const float* mesh   = (const float*)d_in[0];
  const float* bary_w = (const float*)d_in[1];
  const float* W      = (const float*)d_in[2];
  const float* bias   = (const float*)d_in[3];
  const float* coeffs = (const float*)d_in[4];
  const int* bidx     = (const int*)d_in[5];
  float* out = (float*)d_out;
  char* ws = (char*)d_ws;

  __hip_bfloat16* meshq = (__hip_bfloat16*)ws;                    // 12,800,000 B
  float* G              = (float*)(ws + 12800000);                // 1,280 B
  __hip_bfloat16* B2    = (__hip_bfloat16*)(ws + 12801280);       // 2,097,152 B (slot 4MB)
  __hip_bfloat16* Smat  = (__hip_bfloat16*)(ws + 16995584);       // 102,400,000 B
  unsigned* packb       = (unsigned*)(ws + 119395584);            // 24,000,000 B

  int do_pack = (ws_size >= 143395584UL) ? 1 : 0;

  prep_kernel<<<dim3(2048), dim3(256), 0, stream>>>(mesh, coeffs, W, bary_w, bidx,
                                                    meshq, G, B2, packb, do_pack);
  if (do_pack) {
    for (int p = 0; p < 4; ++p)
      s_pass_packed<<<dim3(1563), dim3(256), 0, stream>>>(meshq, packb, G, Smat, p);
  } else {
    for (int p = 0; p < 4; ++p)
      s_pass_kernel<<<dim3(3125), dim3(256), 0, stream>>>(meshq, bary_w, bidx, G, Smat, p);
  }
  gemm_kernel<<<dim3(8, 784), dim3(256), 0, stream>>>(Smat, B2, bias, out);
}

// Round 19
// 373.674 us; speedup vs baseline: 1.0296x; 1.0296x over previous
//
#include <hip/hip_runtime.h>
#include <hip/hip_bf16.h>
#include <stdint.h>

#define NN 50000
#define RR 5
#define AA 8
#define FF 128
#define TT 2
#define OO 128
#define KDIM 1024   // 8 planes * F
#define KB 512      // K per half (E or O)
#define RA 40       // R*A

typedef __attribute__((ext_vector_type(8))) short short8;
typedef __attribute__((ext_vector_type(4))) float f32x4;
typedef __attribute__((ext_vector_type(2))) float f32x2;
typedef __attribute__((ext_vector_type(4))) int i32x4;
typedef __attribute__((ext_vector_type(2))) unsigned u32x2;

#if __has_builtin(__builtin_elementwise_fma)
__device__ inline f32x2 pk_fma(f32x2 a, f32x2 b, f32x2 c) {
  return __builtin_elementwise_fma(a, b, c);
}
#else
__device__ inline f32x2 pk_fma(f32x2 a, f32x2 b, f32x2 c) {
  f32x2 d;
  asm("v_pk_fma_f32 %0, %1, %2, %3" : "=v"(d) : "v"(a), "v"(b), "v"(c));
  return d;
}
#endif

__device__ inline void gload_lds16(const void* g, void* l) {
  __builtin_amdgcn_global_load_lds(
      (const __attribute__((address_space(1))) unsigned int*)g,
      (__attribute__((address_space(3))) unsigned int*)l, 16, 0, 0);
}

// ---------- prep: mesh->bf16 sliced, G (radix-2 mix), B2 (E/O weights in
// MFMA-fragment-major layout), packed bary ----------
__global__ void prep_kernel(const float* __restrict__ mesh,
                            const float* __restrict__ coeffs,
                            const float* __restrict__ W,
                            const float* __restrict__ bary_w,
                            const int* __restrict__ bary_idx,
                            __hip_bfloat16* __restrict__ meshq,  // [4][N][32]
                            float* __restrict__ G,               // [8][40]
                            __hip_bfloat16* __restrict__ B2,     // 2MB frag-major
                            unsigned* __restrict__ packb,
                            int do_pack) {
  int tid = blockIdx.x * blockDim.x + threadIdx.x;
  int stride = gridDim.x * blockDim.x;
  for (int i = tid; i < NN * FF; i += stride) {
    int n = i >> 7, f = i & 127;
    int p = f >> 5, fo = f & 31;
    meshq[((long)p * NN + n) * 32 + fo] = __float2bfloat16(mesh[i]);
  }
  // G[p][k]: p<4 -> C2[p]+C2[p+4];  p>=4 -> C2[p-4]-C2[p]   (C2 = sum_r coeffs)
  for (int i = tid; i < AA * RA; i += stride) {
    int p = i / RA, k = i % RA;
    int a = p & 3;
    float s1 = 0.f, s2 = 0.f;
    for (int r = 0; r < RR; ++r) {
      s1 += coeffs[(r * AA + a) * RA + k];
      s2 += coeffs[(r * AA + a + 4) * RA + k];
    }
    G[i] = (p < 4) ? (s1 + s2) : (s1 - s2);
  }
  // B2: e -> sub=e&7, lane=(e>>3)&63, kt=(e>>9)&15, cg=(e>>13)&63, half=e>>19.
  // col c = cg*16+(lane&15), k = kt*32+(lane>>4)*8+sub; c = o*8+t*4+j.
  for (int e = tid; e < 2048 * KB; e += stride) {
    int sub = e & 7;
    int lane = (e >> 3) & 63;
    int kt = (e >> 9) & 15;
    int cg = (e >> 13) & 63;
    int half = e >> 19;
    int c = cg * 16 + (lane & 15);
    int k = kt * 32 + (lane >> 4) * 8 + sub;
    int o = c >> 3, t = (c >> 2) & 1, j = c & 3;
    int a4 = k >> 7, f = k & 127;
    int m = (a4 + j) & 3;
    float w0 = W[((m * TT + t) * OO + o) * FF + f];
    float w4 = W[(((m + 4) * TT + t) * OO + o) * FF + f];
    float v;
    if (half == 0) v = 0.5f * (w0 + w4);
    else {
      v = 0.5f * (w0 - w4);
      if (a4 + j >= 4) v = -v;
    }
    B2[e] = __float2bfloat16(v);
  }
  if (do_pack) {
    for (int i = tid; i < NN * 120; i += stride) {
      __hip_bfloat16 h = __float2bfloat16(bary_w[i]);
      unsigned wb = *(unsigned short*)&h;
      packb[i] = ((unsigned)bary_idx[i] << 16) | wb;
    }
  }
}

// ---------- S pass (packed, per-slice, 4 features/lane, pk-f32, unroll 2) ----------
// [372.9us-run config — frozen. unroll 4 regressed (R18, -occupancy); fused
// 4-slice regressed 1.7x (R10, L2 overflow). L1-request-bound at ~32us/pass.]
__global__ __launch_bounds__(256) void s_pass_packed(
    const __hip_bfloat16* __restrict__ meshq,
    const unsigned* __restrict__ packb,
    const float* __restrict__ G,
    __hip_bfloat16* __restrict__ Sout,
    int p) {
  __shared__ unsigned pk_s[32 * 120];
  __shared__ float g_s[AA * RA];
  int tid = threadIdx.x;
  long n0 = (long)blockIdx.x * 32;
  int nnode = (NN - n0 < 32) ? (int)(NN - n0) : 32;
  int nvec = nnode * 30;
  const i32x4* psrc = (const i32x4*)(packb + n0 * 120);
  for (int i = tid; i < nvec; i += 256) {
    i32x4 v = __builtin_nontemporal_load(psrc + i);
    ((i32x4*)pk_s)[i] = v;
  }
  for (int i = tid; i < AA * RA; i += 256) g_s[i] = G[i];
  __syncthreads();

  int g = tid >> 3;
  int fo = tid & 7;
  long n = n0 + g;
  if (n >= NN) return;
  const unsigned* pg = pk_s + g * 120;
  const char* mbase = (const char*)meshq + (long)p * NN * 64 + fo * 8;

  f32x2 accA[AA], accB[AA];
#pragma unroll
  for (int a = 0; a < AA; ++a) {
    accA[a] = (f32x2){0.f, 0.f};
    accB[a] = (f32x2){0.f, 0.f};
  }

#pragma unroll 2
  for (int k = 0; k < RA; ++k) {
    f32x2 sA = (f32x2){0.f, 0.f}, sB = (f32x2){0.f, 0.f};
#pragma unroll
    for (int j = 0; j < 3; ++j) {
      unsigned v = pg[k * 3 + j];
      long row = v >> 16;
      float w = __uint_as_float(v << 16);
      f32x2 wv = (f32x2){w, w};
      u32x2 u = *(const u32x2*)(mbase + row * 64);
      f32x2 lo = (f32x2){__uint_as_float(u[0] << 16),
                         __uint_as_float(u[0] & 0xffff0000u)};
      f32x2 hi = (f32x2){__uint_as_float(u[1] << 16),
                         __uint_as_float(u[1] & 0xffff0000u)};
      sA = pk_fma(wv, lo, sA);
      sB = pk_fma(wv, hi, sB);
    }
#pragma unroll
    for (int a = 0; a < AA; ++a) {
      float cc = g_s[a * RA + k];
      f32x2 cv = (f32x2){cc, cc};
      accA[a] = pk_fma(cv, sA, accA[a]);
      accB[a] = pk_fma(cv, sB, accB[a]);
    }
  }

  long base = n * KDIM + p * 32 + fo * 4;
#pragma unroll
  for (int a = 0; a < AA; ++a) {
    __hip_bfloat16 h0 = __float2bfloat16(accA[a][0]);
    __hip_bfloat16 h1 = __float2bfloat16(accA[a][1]);
    __hip_bfloat16 h2 = __float2bfloat16(accB[a][0]);
    __hip_bfloat16 h3 = __float2bfloat16(accB[a][1]);
    unsigned w0 = (unsigned)*(unsigned short*)&h0 |
                  ((unsigned)*(unsigned short*)&h1 << 16);
    unsigned w1 = (unsigned)*(unsigned short*)&h2 |
                  ((unsigned)*(unsigned short*)&h3 << 16);
    u32x2 st = (u32x2){w0, w1};
    __builtin_nontemporal_store(st, (u32x2*)(Sout + base + a * FF));
  }
}

// ---------- S pass (legacy fallback, per-slice) ----------
__global__ __launch_bounds__(256) void s_pass_kernel(
    const __hip_bfloat16* __restrict__ meshq,
    const float* __restrict__ bary_w,
    const int* __restrict__ bary_idx,
    const float* __restrict__ G,
    __hip_bfloat16* __restrict__ Sout,
    int p) {
  __shared__ float w_s[16 * 120];
  __shared__ int i_s[16 * 120];
  __shared__ float g_s[AA * RA];
  int tid = threadIdx.x;
  long n0 = (long)blockIdx.x * 16;
  const f32x4* wsrc = (const f32x4*)(bary_w + n0 * 120);
  const i32x4* isrc = (const i32x4*)(bary_idx + n0 * 120);
  for (int i = tid; i < 480; i += 256) {
    f32x4 wv = __builtin_nontemporal_load(wsrc + i);
    ((f32x4*)w_s)[i] = wv;
    i32x4 iv = __builtin_nontemporal_load(isrc + i);
    ((i32x4*)i_s)[i] = iv;
  }
  for (int i = tid; i < AA * RA; i += 256) g_s[i] = G[i];
  __syncthreads();
  int g = tid >> 4;
  int fo = tid & 15;
  long n = n0 + g;
  const float* wg = w_s + g * 120;
  const int* ig = i_s + g * 120;
  const char* mbase = (const char*)meshq + (long)p * NN * 64 + fo * 4;
  float sx_acc[AA], sy_acc[AA];
#pragma unroll
  for (int a = 0; a < AA; ++a) { sx_acc[a] = 0.f; sy_acc[a] = 0.f; }
#pragma unroll 2
  for (int k = 0; k < RA; ++k) {
    float sx = 0.f, sy = 0.f;
#pragma unroll
    for (int j = 0; j < 3; ++j) {
      int row = ig[k * 3 + j];
      unsigned u = *(const unsigned*)(mbase + (long)row * 64);
      float w = wg[k * 3 + j];
      sx += w * __uint_as_float(u << 16);
      sy += w * __uint_as_float(u & 0xffff0000u);
    }
#pragma unroll
    for (int a = 0; a < AA; ++a) {
      float c = g_s[a * RA + k];
      sx_acc[a] += c * sx;
      sy_acc[a] += c * sy;
    }
  }
  long base = n * KDIM + p * 32 + fo * 2;
#pragma unroll
  for (int a = 0; a < AA; ++a) {
    __hip_bfloat16 hx = __float2bfloat16(sx_acc[a]);
    __hip_bfloat16 hy = __float2bfloat16(sy_acc[a]);
    unsigned u = (unsigned)*(unsigned short*)&hx | ((unsigned)*(unsigned short*)&hy << 16);
    __builtin_nontemporal_store(u, (unsigned*)(Sout + base + a * FF));
  }
}

// ---------- GEMM (radix-2, SMALL-ACC 3-waves/SIMD): block = 64 rows x
// (128E + 128O cols), K=512; 256 thr = 4 waves (2M x 2N); per wave 32 rows x
// 64 cols per half -> acc[2][8] f32x4 = 64 AGPR (VGPR 80, 3 waves/SIMD,
// Occ 32%). [R17/R18 config — frozen: 9 schedule/geometry variants all land
// 210-257us; this is the measured floor of the radix structure.]
__global__ __launch_bounds__(256, 3) void gemm_kernel(
    const __hip_bfloat16* __restrict__ Sh,
    const __hip_bfloat16* __restrict__ B2,
    const float* __restrict__ bias,
    float* __restrict__ out) {
  int bx = blockIdx.x;
  int by = blockIdx.y;
  int cb = by & 7;
  int mt = ((by >> 3) << 3) + bx;
  if (mt >= 782) return;
  int row0 = mt * 64;

  int tid = threadIdx.x;
  int lane = tid & 63;
  int wid = tid >> 6;
  int wave_m = wid >> 1;   // 0..1 (32 rows each)
  int wave_n = wid & 1;    // 0..1 (64 cols each per half)

  __shared__ __align__(16) char lds[49152];

  long srcA[2];
  int dstA[2];
#pragma unroll
  for (int i = 0; i < 2; ++i) {
    int li = i * 256 + tid;
    int plane = li >> 8;
    int r = (li & 255) >> 2, sp = li & 3;
    int sl = sp ^ ((r >> 1) & 3);
    int rowA = row0 + r;
    if (rowA >= NN) rowA = NN - 1;
    srcA[i] = (long)rowA * KDIM + plane * 512 + sl * 8;
    dstA[i] = li * 16;
  }
  const char* b2c = (const char*)B2;
  long srcB[4];
  int dstB[4];
#pragma unroll
  for (int i = 0; i < 4; ++i) {
    int li = i * 256 + tid;
    int half = li >> 9, cgl = (li >> 6) & 7, inner = li & 63;
    srcB[i] = (((long)(half * 64 + cb * 8 + cgl) * 16) * 1024) + inner * 16;
    dstB[i] = 8192 + li * 16;
  }
  int offA[2];
#pragma unroll
  for (int m = 0; m < 2; ++m) {
    int r = wave_m * 32 + m * 16 + (lane & 15);
    int phys = (lane >> 4) ^ ((r >> 1) & 3);
    offA[m] = r * 64 + phys * 16;
  }
  int offB[4];
#pragma unroll
  for (int n = 0; n < 4; ++n)
    offB[n] = 8192 + (wave_n * 4 + n) * 1024 + lane * 16;

  f32x4 acc[2][8];
#pragma unroll
  for (int m = 0; m < 2; ++m)
#pragma unroll
    for (int q = 0; q < 8; ++q) acc[m][q] = (f32x4){0.f, 0.f, 0.f, 0.f};

#define STAGE(T)                                                              \
  {                                                                           \
    char* base_ = lds + ((T) & 1) * 24576;                                    \
    long k0_ = (long)(T) * 32;                                                \
    _Pragma("unroll") for (int i_ = 0; i_ < 2; ++i_)                          \
        gload_lds16(Sh + srcA[i_] + k0_, base_ + dstA[i_]);                   \
    _Pragma("unroll") for (int i_ = 0; i_ < 4; ++i_)                          \
        gload_lds16(b2c + srcB[i_] + (long)(T) * 1024, base_ + dstB[i_]);     \
  }

#define GSTEP(STP, DOSTAGE)                                                   \
  {                                                                           \
    const char* cbuf = lds + ((STP) & 1) * 24576;                             \
    asm volatile("s_waitcnt vmcnt(0)" ::: "memory");                          \
    __builtin_amdgcn_sched_barrier(0);                                        \
    __builtin_amdgcn_s_barrier();                                             \
    __builtin_amdgcn_sched_barrier(0);                                        \
    if (DOSTAGE) STAGE((STP) + 1)                                             \
    __builtin_amdgcn_sched_barrier(0);                                        \
    short8 aE[2], aO[2], bE[4], bO[4];                                        \
    _Pragma("unroll") for (int m_ = 0; m_ < 2; ++m_) {                        \
      aE[m_] = *(const short8*)(cbuf + offA[m_]);                             \
      aO[m_] = *(const short8*)(cbuf + offA[m_] + 4096);                      \
    }                                                                         \
    _Pragma("unroll") for (int n_ = 0; n_ < 4; ++n_) {                        \
      bE[n_] = *(const short8*)(cbuf + offB[n_]);                             \
      bO[n_] = *(const short8*)(cbuf + offB[n_] + 8192);                      \
    }                                                                         \
    __builtin_amdgcn_s_setprio(1);                                            \
    _Pragma("unroll") for (int m_ = 0; m_ < 2; ++m_)                          \
        _Pragma("unroll") for (int n_ = 0; n_ < 4; ++n_) {                    \
      acc[m_][n_] = __builtin_amdgcn_mfma_f32_16x16x32_bf16(                  \
          aE[m_], bE[n_], acc[m_][n_], 0, 0, 0);                              \
      acc[m_][n_ + 4] = __builtin_amdgcn_mfma_f32_16x16x32_bf16(              \
          aO[m_], bO[n_], acc[m_][n_ + 4], 0, 0, 0);                          \
    }                                                                         \
    __builtin_amdgcn_s_setprio(0);                                            \
    __builtin_amdgcn_sched_barrier(0);                                        \
  }

  STAGE(0)
  GSTEP(0, 1)  GSTEP(1, 1)  GSTEP(2, 1)  GSTEP(3, 1)
  GSTEP(4, 1)  GSTEP(5, 1)  GSTEP(6, 1)  GSTEP(7, 1)
  GSTEP(8, 1)  GSTEP(9, 1)  GSTEP(10, 1) GSTEP(11, 1)
  GSTEP(12, 1) GSTEP(13, 1) GSTEP(14, 1) GSTEP(15, 0)

  // ---- epilogue: z = E +- O, +40*bias, relu, t-sum shfl_xor(4) -> lout
  //      (64 rows x 156 floats) -> coalesced float4 copy ----
  __syncthreads();
  float* lout = (float*)lds;
  int c = lane & 15;
  int t = (c >> 2) & 1;
  int j = c & 3;
  int hi = lane >> 4;
  float bq[4];
#pragma unroll
  for (int n = 0; n < 4; ++n) {
    int o_l = wave_n * 8 + n * 2 + (c >> 3);
    bq[n] = 40.f * bias[t * OO + cb * 16 + o_l];
  }
#pragma unroll
  for (int m = 0; m < 2; ++m) {
#pragma unroll
    for (int n = 0; n < 4; ++n) {
      int o_l = wave_n * 8 + n * 2 + (c >> 3);
#pragma unroll
      for (int i = 0; i < 4; ++i) {
        float zE = acc[m][n][i];
        float zO = acc[m][n + 4][i];
        float rlo = fmaxf(zE + zO + bq[n], 0.f);
        float rhi = fmaxf(zE - zO + bq[n], 0.f);
        rlo += __shfl_xor(rlo, 4);
        rhi += __shfl_xor(rhi, 4);
        if (!(lane & 4)) {
          int cl = wave_m * 32 + m * 16 + hi * 4 + i;
          lout[cl * 156 + j * 20 + o_l] = rlo;
          lout[cl * 156 + (j + 4) * 20 + o_l] = rhi;
        }
      }
    }
  }
  __syncthreads();
#pragma unroll
  for (int it = 0; it < 8; ++it) {
    int gi = it * 256 + tid;
    int cl = gi >> 5;
    int rem = gi & 31;
    int kr = rem >> 2, q = rem & 3;
    int grow = row0 + cl;
    if (grow < NN) {
      f32x4 v = *(const f32x4*)(lout + cl * 156 + kr * 20 + q * 4);
      long gaddr = (long)grow * 1024 + kr * 128 + cb * 16 + q * 4;
      __builtin_nontemporal_store(v, (f32x4*)(out + gaddr));
    }
  }
}

extern "C" void kernel_launch(void* const* d_in, const int* in_sizes, int n_in,
                              void* d_out, int out_size, void* d_ws, size_t ws_size,
                              hipStream_t stream) {
  const float* mesh   = (const float*)d_in[0];
  const float* bary_w = (const float*)d_in[1];
  const float* W      = (const float*)d_in[2];
  const float* bias   = (const float*)d_in[3];
  const float* coeffs = (const float*)d_in[4];
  const int* bidx     = (const int*)d_in[5];
  float* out = (float*)d_out;
  char* ws = (char*)d_ws;

  __hip_bfloat16* meshq = (__hip_bfloat16*)ws;                    // 12,800,000 B
  float* G              = (float*)(ws + 12800000);                // 1,280 B
  __hip_bfloat16* B2    = (__hip_bfloat16*)(ws + 12801280);       // 2,097,152 B (slot 4MB)
  __hip_bfloat16* Smat  = (__hip_bfloat16*)(ws + 16995584);       // 102,400,000 B
  unsigned* packb       = (unsigned*)(ws + 119395584);            // 24,000,000 B

  int do_pack = (ws_size >= 143395584UL) ? 1 : 0;

  prep_kernel<<<dim3(2048), dim3(256), 0, stream>>>(mesh, coeffs, W, bary_w, bidx,
                                                    meshq, G, B2, packb, do_pack);
  if (do_pack) {
    for (int p = 0; p < 4; ++p)
      s_pass_packed<<<dim3(1563), dim3(256), 0, stream>>>(meshq, packb, G, Smat, p);
  } else {
    for (int p = 0; p < 4; ++p)
      s_pass_kernel<<<dim3(3125), dim3(256), 0, stream>>>(meshq, bary_w, bidx, G, Smat, p);
  }
  gemm_kernel<<<dim3(8, 784), dim3(256), 0, stream>>>(Smat, B2, bias, out);
}